// Round 3
// baseline (259.068 us; speedup 1.0000x reference)
//
#include <hip/hip_runtime.h>
#include <math.h>

#define EN 16

// One lane per (agent n, neighbor k): 8 lanes per agent within a wave.
// Weights staged in LDS once per block, pre-negated so
//   mono(x) = sum_e w2[e]*__expf(fma(x, -w1[e], -b1[e])) + b2.
// Gate-safety: angle gates depend only on force *direction* (scalar mono
// magnitudes cancel in |cos|), so fast-exp cannot flip a gate.
extern "C" __global__ void __launch_bounds__(256)
sfm_kernel(const float* __restrict__ ego, const float* __restrict__ nei,
           const float* __restrict__ border, const float* __restrict__ rec,
           const float* __restrict__ p_dest, const float* __restrict__ angle,
           const float* __restrict__ rep_w1, const float* __restrict__ rep_b1,
           const float* __restrict__ rep_w2, const float* __restrict__ rep_b2,
           const float* __restrict__ att_w1, const float* __restrict__ att_b1,
           const float* __restrict__ att_w2, const float* __restrict__ att_b2,
           const float* __restrict__ bor_w1, const float* __restrict__ bor_b1,
           const float* __restrict__ bor_w2, const float* __restrict__ bor_b2,
           const float* __restrict__ del_w1, const float* __restrict__ del_b1,
           const float* __restrict__ del_w2, const float* __restrict__ del_b2,
           float* __restrict__ out, int N)
{
    // LDS: [net*16+e] = (-w1[e], -b1[e], w2[e], 0); nets: 0=att,1=rep,2=del,3=bor
    __shared__ float4 wlds[64];
    __shared__ float sconst[8];   // [0..3]=b2 per net, [4]=del_one

    {
        const int t = threadIdx.x;
        if (t < 64) {
            const int net = t >> 4, e = t & 15;
            const float* w1p = (net == 0) ? att_w1 : (net == 1) ? rep_w1 : (net == 2) ? del_w1 : bor_w1;
            const float* b1p = (net == 0) ? att_b1 : (net == 1) ? rep_b1 : (net == 2) ? del_b1 : bor_b1;
            const float* w2p = (net == 0) ? att_w2 : (net == 1) ? rep_w2 : (net == 2) ? del_w2 : bor_w2;
            wlds[t] = make_float4(-w1p[e], -b1p[e], w2p[e], 0.0f);
        } else if (t < 68) {
            const int net = t - 64;
            const float* b2p = (net == 0) ? att_b2 : (net == 1) ? rep_b2 : (net == 2) ? del_b2 : bor_b2;
            sconst[net] = b2p[0];
        }
        __syncthreads();
        if (t == 0) {
            float acc = 0.0f;
#pragma unroll
            for (int e = 0; e < EN; ++e) {
                float4 w = wlds[32 + e];              // del net, x = 1
                acc = fmaf(__expf(w.x + w.y), w.z, acc);
            }
            sconst[4] = acc + sconst[2];
        }
        __syncthreads();
    }

    const int gid = blockIdx.x * blockDim.x + threadIdx.x;
    const int n = gid >> 3;
    const int k = gid & 7;
    if (n >= N) return;
    const int lane = threadIdx.x & 63;
    const int gbase = lane & ~7;

    const float ang = angle[0];
    const float p0 = p_dest[0], p1 = p_dest[1];

    // ego row (broadcast within group)
    const float* er = ego + (size_t)n * 16;
    float4 ea = *(const float4*)(er);
    float4 eb = *(const float4*)(er + 4);
    float4 ec = *(const float4*)(er + 8);
    float4 ed = *(const float4*)(er + 12);
    const float px = ea.y, py = ea.z, vx = ea.w, vy = eb.x;
    const float speed = sqrtf(vx * vx + vy * vy);

    // neighbor row (n,k): 64B lane stride, coalesced
    const float* nb = nei + (size_t)n * 128 + (size_t)k * 16;
    float4 na = *(const float4*)nb;          // id, x, y, vx
    const float nvyv = nb[4];
    const float nid = na.x;

    // recording buffer (n,k)
    float2 rc = *(const float2*)(rec + (size_t)n * 16 + (size_t)k * 2);
    const float bid = rc.x, bct = rc.y;

    // ---- count: wave-uniform fast path ----
    // all bid==0 and all nid!=0  =>  fin all-false  =>  cnt==1 everywhere
    unsigned long long m1 = __ballot(bid != 0.0f);
    unsigned long long m2 = __ballot(nid == 0.0f);
    float cntk;
    if ((m1 | m2) == 0ull) {
        cntk = 1.0f;
    } else {
        // general argsort-select emulation (rare; wave-uniform entry)
        bool fin = (bid == nid);
#pragma unroll
        for (int t = 1; t < 8; ++t)
            fin = fin || (bid == __shfl_xor(nid, t));
        unsigned long long bal = __ballot(fin);
        unsigned finM = (unsigned)((bal >> gbase) & 0xFFull);
        int popcFin = __popc(finM);
        int jsel = 0, cbits = 0;
#pragma unroll
        for (int j = 0; j < 8; ++j) {
            int bit = (finM >> j) & 1;
            if (bit && cbits == k) jsel = j;
            cbits += bit;
        }
        float bctj = __shfl(bct, gbase + jsel);
        cntk = (k < popcFin) ? (bctj + 1.0f) : 1.0f;
    }

    // idx: neighbor id among ego[:,7:15]
    bool match = (nid == eb.w) || (nid == ec.x) || (nid == ec.y) || (nid == ec.z)
              || (nid == ec.w) || (nid == ed.x) || (nid == ed.y) || (nid == ed.z);
    const bool idxk = match && (nid != 0.0f);

    float rx = idxk ? (na.y - px) : 0.0f;
    float ry = idxk ? (na.z - py) : 0.0f;
    float rn = sqrtf(rx * rx + ry * ry);
    float rns = idxk ? rn : 1.0f;
    float dx = rx / rns, dy = ry / rns;

    // repulsion input b
    float sxv = na.w * 0.02f, syv = nvyv * 0.02f;
    float ox = rx + sxv, oy = ry + syv;
    float bsum = rn + (ox * ox + oy * oy) - (sxv * sxv + syv * syv);
    float bgate = idxk ? bsum : 1.0f;
    float bb = sqrtf(fmaxf(bgate, 1e-12f)) * 0.5f;

    // fused att(rn) + rep(bb) mono evals from LDS
    float acca = 0.0f, accr = 0.0f;
#pragma unroll
    for (int e = 0; e < EN; ++e) {
        float4 wa = wlds[e];
        float4 wr = wlds[16 + e];
        acca = fmaf(__expf(fmaf(rn, wa.x, wa.y)), wa.z, acca);
        accr = fmaf(__expf(fmaf(bb, wr.x, wr.y)), wr.z, accr);
    }
    float att = acca + sconst[0];
    float rep = accr + sconst[1];

    // del: cnt==1 (always in fast path) -> cached del_one; else eval
    float del;
    if (cntk == 1.0f) {
        del = sconst[4];
    } else {
        float accd = 0.0f;
#pragma unroll
        for (int e = 0; e < EN; ++e) {
            float4 wd = wlds[32 + e];
            accd = fmaf(__expf(fmaf(cntk, wd.x, wd.y)), wd.z, accd);
        }
        del = accd + sconst[2];
    }

    float nbx = 0.0f, nby = 0.0f;
    {
        float sa = del * att;
        float fax = idxk ? sa * dx : 0.0f;
        float fay = idxk ? sa * dy : 0.0f;
        float num = vx * fax + vy * fay;
        float fn = sqrtf(fax * fax + fay * fay);
        float den = fmaxf(speed * fn, 1e-8f);
        if (fabsf(num / den) > ang) { nbx += fax; nby += fay; }
    }
    {
        float frx = idxk ? rep * dx : 0.0f;
        float fry = idxk ? rep * dy : 0.0f;
        float num = vx * frx + vy * fry;
        float fn = sqrtf(frx * frx + fry * fry);
        float den = fmaxf(speed * fn, 1e-8f);
        if (fabsf(num / den) > ang) { nbx += frx; nby += fry; }
    }

    // border: only lanes k<2 (one masked region; 16/64 lanes active)
    float bory = 0.0f;
    if (k < 2) {
        float bsel = (k == 0) ? border[0] : border[3];
        float rb = py - bsel;
        float rbn = fabsf(rb);
        float accb = 0.0f;
#pragma unroll
        for (int e = 0; e < EN; ++e) {
            float4 wb = wlds[48 + e];
            accb = fmaf(__expf(fmaf(rbn, wb.x, wb.y)), wb.z, accb);
        }
        float mb = accb + sconst[3];
        float fby = mb * (rb / rbn);
        float num = vy * fby;
        float den = fmaxf(speed * fabsf(fby), 1e-8f);
        if (fabsf(num / den) > ang) bory = fby;
    }

    // xor-butterfly sum over the 8-lane group
#pragma unroll
    for (int m = 1; m < 8; m <<= 1) {
        nbx  += __shfl_xor(nbx,  m);
        nby  += __shfl_xor(nby,  m);
        bory += __shfl_xor(bory, m);
    }

    // destination force (uniform across group)
    float fdx = (p1 * speed - vx) / p0;
    float fdy = (0.0f - vy) / p0;
    float fdex = 0.0f, fdey = 0.0f;
    {
        float num = vx * fdx + vy * fdy;
        float fn = sqrtf(fdx * fdx + fdy * fdy);
        float den = fmaxf(speed * fn, 1e-8f);
        if (fabsf(num / den) > ang) { fdex = fdx; fdey = fdy; }
    }

    // output (N,3,2): lanes 0..5 write one float each
    float wv = (k == 0) ? fdex
             : (k == 1) ? fdey
             : (k == 2) ? nbx
             : (k == 3) ? nby
             : (k == 4) ? 0.0f
             : bory;
    if (k < 6) out[(size_t)n * 6 + k] = wv;
}

extern "C" void kernel_launch(void* const* d_in, const int* in_sizes, int n_in,
                              void* d_out, int out_size, void* d_ws, size_t ws_size,
                              hipStream_t stream) {
    const float* ego    = (const float*)d_in[0];
    const float* nei    = (const float*)d_in[1];
    const float* border = (const float*)d_in[2];
    const float* rec    = (const float*)d_in[3];
    const float* p_dest = (const float*)d_in[4];
    const float* angle  = (const float*)d_in[5];
    const float* rep_w1 = (const float*)d_in[6];
    const float* rep_b1 = (const float*)d_in[7];
    const float* rep_w2 = (const float*)d_in[8];
    const float* rep_b2 = (const float*)d_in[9];
    const float* att_w1 = (const float*)d_in[10];
    const float* att_b1 = (const float*)d_in[11];
    const float* att_w2 = (const float*)d_in[12];
    const float* att_b2 = (const float*)d_in[13];
    const float* bor_w1 = (const float*)d_in[14];
    const float* bor_b1 = (const float*)d_in[15];
    const float* bor_w2 = (const float*)d_in[16];
    const float* bor_b2 = (const float*)d_in[17];
    const float* del_w1 = (const float*)d_in[18];
    const float* del_b1 = (const float*)d_in[19];
    const float* del_w2 = (const float*)d_in[20];
    const float* del_b2 = (const float*)d_in[21];
    float* out = (float*)d_out;

    int N = in_sizes[0] / 16;
    long long threads = (long long)N * 8;
    dim3 grid((unsigned)((threads + 255) / 256));
    sfm_kernel<<<grid, 256, 0, stream>>>(
        ego, nei, border, rec, p_dest, angle,
        rep_w1, rep_b1, rep_w2, rep_b2,
        att_w1, att_b1, att_w2, att_b2,
        bor_w1, bor_b1, bor_w2, bor_b2,
        del_w1, del_b1, del_w2, del_b2,
        out, N);
}